// Round 1
// baseline (534.862 us; speedup 1.0000x reference)
//
#include <hip/hip_runtime.h>
#include <math.h>

#define BROWS 8192
#define FIN   512
#define FOUT  512
#define MMIX  8

#define BB 4     // b rows per block (one per wave)
#define BO 128   // o columns per block (2 per lane)
#define CF 64    // f chunk

// ws layout (floats): [0..7] softmax weights; [16 .. 16+512*16) T table
// T[f*16 + m]   = mean_p[m][f]          (m<8)
// T[f*16 + 8+m] = exp(log_std2[m][f])

__global__ __launch_bounds__(256) void gmm_prep(const float* __restrict__ mean_p,
                                                const float* __restrict__ log_std2,
                                                const float* __restrict__ lw,
                                                float* __restrict__ ws) {
    int idx = blockIdx.x * 256 + threadIdx.x;
    if (idx == 0) {
        float mx = lw[0];
        for (int m = 1; m < MMIX; ++m) mx = fmaxf(mx, lw[m]);
        float e[MMIX]; float s = 0.f;
        for (int m = 0; m < MMIX; ++m) { e[m] = expf(lw[m] - mx); s += e[m]; }
        for (int m = 0; m < MMIX; ++m) ws[m] = e[m] / s;
    }
    if (idx < FIN * 16) {
        int f = idx >> 4, m = idx & 15;
        float v = (m < 8) ? mean_p[m * FIN + f] : expf(log_std2[(m - 8) * FIN + f]);
        ws[16 + idx] = v;
    }
}

__global__ __launch_bounds__(256) void gmm_main(const float* __restrict__ x,
                                                const float* __restrict__ W,
                                                const float* __restrict__ bias,
                                                const float* __restrict__ ws,
                                                float* __restrict__ out) {
    __shared__ float wt[CF][BO + 1];   // transposed W tile, stride 129 -> 2-way (free)
    __shared__ float xs[BB][CF];       // cleaned x chunk per wave

    const int tid  = threadIdx.x;
    const int lane = tid & 63;
    const int wid  = tid >> 6;
    const int obase = blockIdx.x * BO;
    const int brow  = blockIdx.y * BB + wid;

    const float* __restrict__ T    = ws + 16;
    const float* __restrict__ xrow = x + (size_t)brow * FIN;

    float base0 = 0.f, base1 = 0.f;
    float cn0[8], cn1[8], cd0[8], cd1[8];
#pragma unroll
    for (int m = 0; m < 8; ++m) { cn0[m] = 0.f; cn1[m] = 0.f; cd0[m] = 0.f; cd1[m] = 0.f; }
    bool empty = false;

    for (int c = 0; c < FIN / CF; ++c) {
        __syncthreads();   // previous chunk's readers done before overwrite
        // ---- stage W tile transposed: wt[f_local][o_local] ----
#pragma unroll
        for (int i = 0; i < 8; ++i) {
            int idx = i * 256 + tid;          // 0..2047, 4 floats each
            int fl  = (idx & 15) << 2;        // 0..60 step 4
            int ol  = idx >> 4;               // 0..127
            float4 w4 = *(const float4*)(W + (size_t)(obase + ol) * FIN + c * CF + fl);
            wt[fl + 0][ol] = w4.x;
            wt[fl + 1][ol] = w4.y;
            wt[fl + 2][ol] = w4.z;
            wt[fl + 3][ol] = w4.w;
        }
        // ---- stage x chunk for this wave's row; build NaN ballot ----
        float v = xrow[c * CF + lane];
        bool isn = (v != v);
        unsigned long long nm = __ballot(isn);
        empty = empty || (nm != 0ull);
        xs[wid][lane] = isn ? 0.f : v;
        __syncthreads();

        const float* __restrict__ tpc = T + (size_t)c * CF * 16;
#pragma unroll 4
        for (int l = 0; l < CF; ++l) {
            float xv = xs[wid][l];            // broadcast read
            float w0 = wt[l][lane];
            float w1 = wt[l][lane + 64];
            if (!((nm >> l) & 1ull)) {        // wave-uniform branch
                base0 = fmaf(xv, w0, base0);
                base1 = fmaf(xv, w1, base1);
            } else {
                const float* tp = tpc + l * 16;   // wave-uniform -> scalar loads
                float w0s = w0 * w0, w1s = w1 * w1;
#pragma unroll
                for (int m = 0; m < 8; ++m) {
                    float mp = tp[m];
                    float vr = tp[8 + m];
                    cn0[m] = fmaf(mp, w0, cn0[m]);
                    cn1[m] = fmaf(mp, w1, cn1[m]);
                    cd0[m] = fmaf(vr, w0s, cd0[m]);
                    cd1[m] = fmaf(vr, w1s, cd1[m]);
                }
            }
        }
    }

    // ---- epilogue ----
    float sw[8];
#pragma unroll
    for (int m = 0; m < 8; ++m) sw[m] = ws[m];

    const size_t orow = (size_t)brow * FOUT;

    auto epi = [&](float basev, const float* cn, const float* cd, int o) {
        float bo = bias[o];
        float mix = 0.f, num0 = 0.f;
#pragma unroll
        for (int m = 0; m < 8; ++m) {
            float num = basev + cn[m] + bo;
            if (m == 0) num0 = num;
            float den = sqrtf(cd[m]);
            float z   = num / (den + 1e-9f);
            float pdf = 0.3989422804014327f * expf(-0.5f * z * z);
            float cdf = 0.5f * (1.0f + erff(z * 0.70710678118654752f));
            float nr  = den * (pdf + z * cdf);
            mix = fmaf(sw[m], nr, mix);
        }
        out[orow + o] = empty ? mix : fmaxf(num0, 0.f);
    };
    epi(base0, cn0, cd0, obase + lane);
    epi(base1, cn1, cd1, obase + lane + 64);
}

extern "C" void kernel_launch(void* const* d_in, const int* in_sizes, int n_in,
                              void* d_out, int out_size, void* d_ws, size_t ws_size,
                              hipStream_t stream) {
    const float* x        = (const float*)d_in[0];
    const float* W        = (const float*)d_in[1];
    const float* bvec     = (const float*)d_in[2];
    const float* mean_p   = (const float*)d_in[3];
    const float* log_std2 = (const float*)d_in[4];
    const float* lw       = (const float*)d_in[5];
    float* out = (float*)d_out;
    float* ws  = (float*)d_ws;

    gmm_prep<<<dim3((FIN * 16 + 255) / 256), 256, 0, stream>>>(mean_p, log_std2, lw, ws);
    gmm_main<<<dim3(FOUT / BO, BROWS / BB), 256, 0, stream>>>(x, W, bvec, ws, out);
}

// Round 2
// 217.465 us; speedup vs baseline: 2.4595x; 2.4595x over previous
//
#include <hip/hip_runtime.h>
#include <math.h>

typedef __attribute__((ext_vector_type(8))) short short8;
typedef __attribute__((ext_vector_type(4))) float floatx4;

#define B_ROWS 8192
#define FIN    512
#define FOUT   512

// ---- workspace layout ----
// float region (offsets in floats from ws base):
#define WSF_SW   0          // 8 softmax weights
#define WSF_T    1024       // 8192: T[f*16+m]=mean_p[m][f], T[f*16+8+m]=exp(ls2[m][f])
#define WSF_WT   16384      // 262144: W^T fp32 [f][o]
#define WSF_BASE 524288     // 8192*512 fp32 base GEMM result
// byte offsets:
#define WSB_WB   18874368UL // 512*512 bf16 W row-major [o][f]
#define WSB_XCB  19398656UL // 8192*512 bf16 cleaned x
#define WSB_NIDX 27787264UL // 8192*512 int nan indices (compacted per row)
#define WSB_CNT  44564480UL // 8192 int counts

__device__ inline unsigned short f2bf(float f) {
    unsigned u = __builtin_bit_cast(unsigned, f);
    u += 0x7fffu + ((u >> 16) & 1u);
    return (unsigned short)(u >> 16);
}

// ---------------- prep: W transpose + bf16 W + T table + softmax ----------------
__global__ __launch_bounds__(256) void prep_w(const float* __restrict__ W,
                                              const float* __restrict__ mean_p,
                                              const float* __restrict__ ls2,
                                              const float* __restrict__ lw,
                                              float* __restrict__ wsf,
                                              unsigned short* __restrict__ Wb) {
    int blk = blockIdx.x, tid = threadIdx.x;
    if (blk < 1024) {
        int idx = blk * 256 + tid;            // o*512 + f
        float w = W[idx];
        int o = idx >> 9, f = idx & 511;
        wsf[WSF_WT + f * 512 + o] = w;
        Wb[idx] = f2bf(w);
    } else if (blk < 1056) {
        int idx = (blk - 1024) * 256 + tid;   // f*16 + m
        int f = idx >> 4, m = idx & 15;
        float v = (m < 8) ? mean_p[m * 512 + f] : expf(ls2[(m - 8) * 512 + f]);
        wsf[WSF_T + idx] = v;
    } else if (tid == 0) {
        float mx = lw[0];
        for (int m = 1; m < 8; ++m) mx = fmaxf(mx, lw[m]);
        float e[8]; float s = 0.f;
        for (int m = 0; m < 8; ++m) { e[m] = expf(lw[m] - mx); s += e[m]; }
        for (int m = 0; m < 8; ++m) wsf[WSF_SW + m] = e[m] / s;
    }
}

// ---------------- prep: per-row clean x (bf16) + compacted NaN index list ----------------
__global__ __launch_bounds__(256) void prep_rows(const float* __restrict__ x,
                                                 unsigned short* __restrict__ xcb,
                                                 int* __restrict__ nidx,
                                                 int* __restrict__ cnts) {
    int tid = threadIdx.x, lane = tid & 63, wid = tid >> 6;
    int row = blockIdx.x * 4 + wid;
    const float* xr = x + (size_t)row * FIN;
    int cnt = 0;
    for (int c = 0; c < FIN / 64; ++c) {
        float v = xr[c * 64 + lane];
        bool isn = (v != v);
        unsigned long long nm = __ballot(isn);
        if (isn) {
            int rank = (int)__popcll(nm & ((1ull << lane) - 1ull));
            nidx[(size_t)row * 512 + cnt + rank] = c * 64 + lane;
        }
        cnt += (int)__popcll(nm);
        xcb[(size_t)row * FIN + c * 64 + lane] = f2bf(isn ? 0.f : v);
    }
    if (lane == 0) cnts[row] = cnt;
}

// ---------------- base GEMM: base[b,o] = sum_f xcb[b,f]*Wb[o,f]  (bf16 MFMA) ----------------
// tile 128(M) x 64(N), BK=64, 4 waves in 2x2 (each 64x32)
__global__ __launch_bounds__(256) void gemm_base(const unsigned short* __restrict__ xcb,
                                                 const unsigned short* __restrict__ Wb,
                                                 float* __restrict__ base) {
    __shared__ short As[128 * 64];
    __shared__ short Bs[64 * 64];
    int tid = threadIdx.x, lane = tid & 63, wid = tid >> 6;
    int wr = wid >> 1, wc = wid & 1;
    int bb0 = blockIdx.y * 128;
    int ob0 = blockIdx.x * 64;

    floatx4 acc[4][2];
#pragma unroll
    for (int mi = 0; mi < 4; ++mi)
#pragma unroll
        for (int ni = 0; ni < 2; ++ni) acc[mi][ni] = (floatx4){0.f, 0.f, 0.f, 0.f};

    for (int ks = 0; ks < FIN; ks += 64) {
        __syncthreads();
#pragma unroll
        for (int i = 0; i < 4; ++i) {                 // A: 1024 chunks of 8 bf16
            int cid = i * 256 + tid, row = cid >> 3, c = cid & 7;
            short8 v = *(const short8*)(xcb + (((size_t)(bb0 + row)) << 9) + ks + c * 8);
            *(short8*)(&As[row * 64 + ((c ^ (row & 7)) << 3)]) = v;
        }
#pragma unroll
        for (int i = 0; i < 2; ++i) {                 // B: 512 chunks
            int cid = i * 256 + tid, row = cid >> 3, c = cid & 7;
            short8 v = *(const short8*)(Wb + (((size_t)(ob0 + row)) << 9) + ks + c * 8);
            *(short8*)(&Bs[row * 64 + ((c ^ (row & 7)) << 3)]) = v;
        }
        __syncthreads();
#pragma unroll
        for (int kk = 0; kk < 2; ++kk) {
            short8 av[4], bv[2];
#pragma unroll
            for (int mi = 0; mi < 4; ++mi) {
                int row = wr * 64 + mi * 16 + (lane & 15);
                int c = kk * 4 + (lane >> 4);
                av[mi] = *(const short8*)(&As[row * 64 + ((c ^ (row & 7)) << 3)]);
            }
#pragma unroll
            for (int ni = 0; ni < 2; ++ni) {
                int row = wc * 32 + ni * 16 + (lane & 15);
                int c = kk * 4 + (lane >> 4);
                bv[ni] = *(const short8*)(&Bs[row * 64 + ((c ^ (row & 7)) << 3)]);
            }
#pragma unroll
            for (int mi = 0; mi < 4; ++mi)
#pragma unroll
                for (int ni = 0; ni < 2; ++ni)
                    acc[mi][ni] = __builtin_amdgcn_mfma_f32_16x16x32_bf16(av[mi], bv[ni], acc[mi][ni], 0, 0, 0);
        }
    }
#pragma unroll
    for (int mi = 0; mi < 4; ++mi)
#pragma unroll
        for (int ni = 0; ni < 2; ++ni)
#pragma unroll
            for (int r = 0; r < 4; ++r) {
                int row = bb0 + wr * 64 + mi * 16 + (lane >> 4) * 4 + r;
                int col = ob0 + wc * 32 + ni * 16 + (lane & 15);
                base[(size_t)row * FOUT + col] = acc[mi][ni][r];
            }
}

// ---------------- heavy: sparse corrections over NaN list + epilogue ----------------
__device__ inline float epi_one(float basev, const float* cn, const float* cd,
                                float biasv, const float* sw, bool empty) {
    float mix = 0.f, num0 = 0.f;
#pragma unroll
    for (int m = 0; m < 8; ++m) {
        float num = basev + cn[m] + biasv;
        if (m == 0) num0 = num;
        float den = sqrtf(cd[m]);
        float z = num / (den + 1e-9f);
        float pdf = 0.3989422804014327f * expf(-0.5f * z * z);
        float cdf = 0.5f * (1.0f + erff(z * 0.70710678118654752f));
        mix = fmaf(sw[m], den * (pdf + z * cdf), mix);
    }
    return empty ? mix : fmaxf(num0, 0.f);
}

__global__ __launch_bounds__(256) void gmm_heavy(const float* __restrict__ wsf,
                                                 const int* __restrict__ nidx,
                                                 const int* __restrict__ cnts,
                                                 const float* __restrict__ bias,
                                                 float* __restrict__ out) {
    const float* T    = wsf + WSF_T;
    const float* Wt   = wsf + WSF_WT;
    const float* base = wsf + WSF_BASE;

    int b = blockIdx.x;
    int tid = threadIdx.x, lane = tid & 63, wid = tid >> 6;
    int oa = wid * 128 + lane * 2;          // this lane's two o's: oa, oa+1
    int cnt = cnts[b];
    const int* nrow = nidx + (size_t)b * 512;

    float cn0[8], cn1[8], cd0[8], cd1[8];
#pragma unroll
    for (int m = 0; m < 8; ++m) { cn0[m] = 0.f; cn1[m] = 0.f; cd0[m] = 0.f; cd1[m] = 0.f; }

    if (cnt > 0) {
        int f = nrow[0];
        float2 wv = *(const float2*)(Wt + (size_t)f * 512 + oa);
        float4 t0 = *(const float4*)(T + f * 16);
        float4 t1 = *(const float4*)(T + f * 16 + 4);
        float4 t2 = *(const float4*)(T + f * 16 + 8);
        float4 t3 = *(const float4*)(T + f * 16 + 12);
        for (int k = 0; k < cnt; ++k) {
            int fn = (k + 1 < cnt) ? nrow[k + 1] : f;
            float2 wvn = *(const float2*)(Wt + (size_t)fn * 512 + oa);
            float4 n0 = *(const float4*)(T + fn * 16);
            float4 n1 = *(const float4*)(T + fn * 16 + 4);
            float4 n2 = *(const float4*)(T + fn * 16 + 8);
            float4 n3 = *(const float4*)(T + fn * 16 + 12);

            float w0 = wv.x, w1 = wv.y;
            float w0s = w0 * w0, w1s = w1 * w1;
            float mp[8] = {t0.x, t0.y, t0.z, t0.w, t1.x, t1.y, t1.z, t1.w};
            float vr[8] = {t2.x, t2.y, t2.z, t2.w, t3.x, t3.y, t3.z, t3.w};
#pragma unroll
            for (int m = 0; m < 8; ++m) {
                cn0[m] = fmaf(mp[m], w0, cn0[m]);
                cn1[m] = fmaf(mp[m], w1, cn1[m]);
                cd0[m] = fmaf(vr[m], w0s, cd0[m]);
                cd1[m] = fmaf(vr[m], w1s, cd1[m]);
            }
            wv = wvn; t0 = n0; t1 = n1; t2 = n2; t3 = n3;
        }
    }

    float sw[8];
#pragma unroll
    for (int m = 0; m < 8; ++m) sw[m] = wsf[WSF_SW + m];

    float2 bs = *(const float2*)(base + (size_t)b * FOUT + oa);
    float2 bi = *(const float2*)(bias + oa);
    bool empty = cnt > 0;
    float2 res;
    res.x = epi_one(bs.x, cn0, cd0, bi.x, sw, empty);
    res.y = epi_one(bs.y, cn1, cd1, bi.y, sw, empty);
    *(float2*)(out + (size_t)b * FOUT + oa) = res;
}

extern "C" void kernel_launch(void* const* d_in, const int* in_sizes, int n_in,
                              void* d_out, int out_size, void* d_ws, size_t ws_size,
                              hipStream_t stream) {
    const float* x        = (const float*)d_in[0];
    const float* W        = (const float*)d_in[1];
    const float* bvec     = (const float*)d_in[2];
    const float* mean_p   = (const float*)d_in[3];
    const float* log_std2 = (const float*)d_in[4];
    const float* lw       = (const float*)d_in[5];
    float* out = (float*)d_out;

    float* wsf = (float*)d_ws;
    unsigned short* Wb  = (unsigned short*)((char*)d_ws + WSB_WB);
    unsigned short* xcb = (unsigned short*)((char*)d_ws + WSB_XCB);
    int* nidx = (int*)((char*)d_ws + WSB_NIDX);
    int* cnts = (int*)((char*)d_ws + WSB_CNT);

    prep_w<<<1057, 256, 0, stream>>>(W, mean_p, log_std2, lw, wsf, Wb);
    prep_rows<<<B_ROWS / 4, 256, 0, stream>>>(x, xcb, nidx, cnts);
    gemm_base<<<dim3(FOUT / 64, B_ROWS / 128), 256, 0, stream>>>(xcb, Wb, wsf + WSF_BASE);
    gmm_heavy<<<B_ROWS, 256, 0, stream>>>(wsf, nidx, cnts, bvec, out);
}

// Round 3
// 198.343 us; speedup vs baseline: 2.6967x; 1.0964x over previous
//
#include <hip/hip_runtime.h>
#include <math.h>

typedef __attribute__((ext_vector_type(8))) short short8;
typedef __attribute__((ext_vector_type(8))) _Float16 f16x8;
typedef __attribute__((ext_vector_type(4))) float floatx4;

#define B_ROWS 8192
#define FIN    512
#define FOUT   512

// ---- workspace byte offsets ----
#define WSB_SW   0UL         // 8 floats
#define WSB_CNT  64UL        // 8192 int
#define WSB_BASE 65536UL     // 8192*512 fp32
#define WSB_XCH  16842752UL  // 8192*512 f16 cleaned x
#define WSB_MSK  25231360UL  // 8192*512 f16 mask (1.0/0.0)
#define WSB_WH   33619968UL  // 512*512 f16 W [o][f]
#define WSB_BCT  34144256UL  // 8192*512 f16 BcT[n=o*16+t][f]

__device__ __forceinline__ void gl2lds16(const void* g, void* l) {
    __builtin_amdgcn_global_load_lds((const __attribute__((address_space(1))) void*)g,
                                     (__attribute__((address_space(3))) void*)l,
                                     16, 0, 0);
}

// ---------------- prep: W f16 + softmax ----------------
__global__ __launch_bounds__(256) void prep_w(const float* __restrict__ W,
                                              const float* __restrict__ lw,
                                              float* __restrict__ wsf,
                                              _Float16* __restrict__ Wh) {
    int blk = blockIdx.x, tid = threadIdx.x;
    if (blk < 1024) {
        int idx = blk * 256 + tid;
        Wh[idx] = (_Float16)W[idx];
    } else if (tid == 0) {
        float mx = lw[0];
        for (int m = 1; m < 8; ++m) mx = fmaxf(mx, lw[m]);
        float e[8]; float s = 0.f;
        for (int m = 0; m < 8; ++m) { e[m] = expf(lw[m] - mx); s += e[m]; }
        for (int m = 0; m < 8; ++m) wsf[m] = e[m] / s;
    }
}

// ---------------- prep: BcT[n][f], n = o*16+t ----------------
__global__ __launch_bounds__(256) void prep_bct(const float* __restrict__ W,
                                                const float* __restrict__ mean_p,
                                                const float* __restrict__ ls2,
                                                _Float16* __restrict__ bct) {
    int tid = threadIdx.x;
    int n  = blockIdx.x * 4 + (tid >> 6);
    int fc = (tid & 63) << 3;
    int o = n >> 4, t = n & 15;
    const float* wp = W + (size_t)o * FIN + fc;
    f16x8 hv;
    if (t < 8) {
        const float* mp = mean_p + (size_t)t * FIN + fc;
#pragma unroll
        for (int j = 0; j < 8; ++j) hv[j] = (_Float16)(mp[j] * wp[j]);
    } else {
        const float* lp = ls2 + (size_t)(t - 8) * FIN + fc;
#pragma unroll
        for (int j = 0; j < 8; ++j) hv[j] = (_Float16)(expf(lp[j]) * wp[j] * wp[j]);
    }
    *(f16x8*)(bct + (size_t)n * FIN + fc) = hv;
}

// ---------------- prep: cleaned x f16 + mask f16 + counts ----------------
__global__ __launch_bounds__(256) void prep_rows(const float* __restrict__ x,
                                                 _Float16* __restrict__ xch,
                                                 _Float16* __restrict__ msk,
                                                 int* __restrict__ cnts) {
    int tid = threadIdx.x, lane = tid & 63, wid = tid >> 6;
    int row = blockIdx.x * 4 + wid;
    const float* xr = x + (size_t)row * FIN;
    int cnt = 0;
#pragma unroll
    for (int c = 0; c < FIN / 64; ++c) {
        float v = xr[c * 64 + lane];
        bool isn = (v != v);
        cnt += (int)__popcll(__ballot(isn));
        xch[(size_t)row * FIN + c * 64 + lane] = (_Float16)(isn ? 0.f : v);
        msk[(size_t)row * FIN + c * 64 + lane] = (_Float16)(isn ? 1.f : 0.f);
    }
    if (lane == 0) cnts[row] = cnt;
}

// ---------------- base GEMM: base[b,o] = sum_f xch[b,f]*Wh[o,f] (f16 MFMA) ----------------
__global__ __launch_bounds__(256) void gemm_base(const _Float16* __restrict__ xch,
                                                 const _Float16* __restrict__ Wh,
                                                 float* __restrict__ base) {
    __shared__ short As[128 * 64];
    __shared__ short Bs[64 * 64];
    int tid = threadIdx.x, lane = tid & 63, wid = tid >> 6;
    int wr = wid >> 1, wc = wid & 1;
    int bb0 = blockIdx.y * 128;
    int ob0 = blockIdx.x * 64;

    floatx4 acc[4][2];
#pragma unroll
    for (int mi = 0; mi < 4; ++mi)
#pragma unroll
        for (int ni = 0; ni < 2; ++ni) acc[mi][ni] = (floatx4){0.f, 0.f, 0.f, 0.f};

    for (int ks = 0; ks < FIN; ks += 64) {
        __syncthreads();
#pragma unroll
        for (int i = 0; i < 4; ++i) {
            int cid = i * 256 + tid, row = cid >> 3, c = cid & 7;
            short8 v = *(const short8*)((const short*)xch + (((size_t)(bb0 + row)) << 9) + ks + c * 8);
            *(short8*)(&As[row * 64 + ((c ^ (row & 7)) << 3)]) = v;
        }
#pragma unroll
        for (int i = 0; i < 2; ++i) {
            int cid = i * 256 + tid, row = cid >> 3, c = cid & 7;
            short8 v = *(const short8*)((const short*)Wh + (((size_t)(ob0 + row)) << 9) + ks + c * 8);
            *(short8*)(&Bs[row * 64 + ((c ^ (row & 7)) << 3)]) = v;
        }
        __syncthreads();
#pragma unroll
        for (int kk = 0; kk < 2; ++kk) {
            f16x8 av[4], bv[2];
#pragma unroll
            for (int mi = 0; mi < 4; ++mi) {
                int row = wr * 64 + mi * 16 + (lane & 15);
                int c = kk * 4 + (lane >> 4);
                av[mi] = *(const f16x8*)(&As[row * 64 + ((c ^ (row & 7)) << 3)]);
            }
#pragma unroll
            for (int ni = 0; ni < 2; ++ni) {
                int row = wc * 32 + ni * 16 + (lane & 15);
                int c = kk * 4 + (lane >> 4);
                bv[ni] = *(const f16x8*)(&Bs[row * 64 + ((c ^ (row & 7)) << 3)]);
            }
#pragma unroll
            for (int mi = 0; mi < 4; ++mi)
#pragma unroll
                for (int ni = 0; ni < 2; ++ni)
                    acc[mi][ni] = __builtin_amdgcn_mfma_f32_16x16x32_f16(av[mi], bv[ni], acc[mi][ni], 0, 0, 0);
        }
    }
#pragma unroll
    for (int mi = 0; mi < 4; ++mi)
#pragma unroll
        for (int ni = 0; ni < 2; ++ni)
#pragma unroll
            for (int r = 0; r < 4; ++r) {
                int row = bb0 + wr * 64 + mi * 16 + (lane >> 4) * 4 + r;
                int col = ob0 + wc * 32 + ni * 16 + (lane & 15);
                base[(size_t)row * FOUT + col] = acc[mi][ni][r];
            }
}

// ---------------- fused mask-GEMM + epilogue ----------------
// C[b, n=o*16+t] = sum_f mask[b,f] * BcT[n,f]; tile 128x128, BK=64, 4 waves 2x2
__global__ __launch_bounds__(256) void gmm_fused(const _Float16* __restrict__ msk,
                                                 const _Float16* __restrict__ bct,
                                                 const float* __restrict__ wsf,
                                                 const int* __restrict__ cnts,
                                                 const float* __restrict__ basebuf,
                                                 const float* __restrict__ bias,
                                                 float* __restrict__ out) {
    __shared__ char lds[32768];
    char* AsB = lds;
    char* BsB = lds + 16384;

    int tid = threadIdx.x, lane = tid & 63, wid = tid >> 6;
    int wr = wid >> 1, wc = wid & 1;

    // 8x8 grouped ordering for L2 locality
    int id = blockIdx.x, gid = id >> 6, wi = id & 63;
    int my = (gid >> 3) * 8 + (wi >> 3);
    int nx = (gid & 7) * 8 + (wi & 7);
    int b0 = my * 128, n0 = nx * 128;

    const char* mB = (const char*)msk;
    const char* bB = (const char*)bct;

    float swv[8];
#pragma unroll
    for (int m = 0; m < 8; ++m) swv[m] = wsf[m];

    floatx4 acc[4][4];
#pragma unroll
    for (int mi = 0; mi < 4; ++mi)
#pragma unroll
        for (int ni = 0; ni < 4; ++ni) acc[mi][ni] = (floatx4){0.f, 0.f, 0.f, 0.f};

    for (int ks = 0; ks < FIN; ks += 64) {
        __syncthreads();
#pragma unroll
        for (int j = 0; j < 4; ++j) {
            int row = (wid * 4 + j) * 8 + (lane >> 3);
            int c = lane & 7;
            gl2lds16(mB + (size_t)(b0 + row) * 1024 + ks * 2 + ((c ^ (row & 7)) << 4),
                     AsB + (wid * 4 + j) * 1024);
            gl2lds16(bB + (size_t)(n0 + row) * 1024 + ks * 2 + ((c ^ (row & 7)) << 4),
                     BsB + (wid * 4 + j) * 1024);
        }
        __syncthreads();
#pragma unroll
        for (int kk = 0; kk < 2; ++kk) {
            f16x8 av[4], bv[4];
#pragma unroll
            for (int mi = 0; mi < 4; ++mi) {
                int row = wr * 64 + mi * 16 + (lane & 15);
                int c = kk * 4 + (lane >> 4);
                av[mi] = *(const f16x8*)(AsB + row * 128 + ((c ^ (row & 7)) << 4));
            }
#pragma unroll
            for (int ni = 0; ni < 4; ++ni) {
                int row = wc * 64 + ni * 16 + (lane & 15);
                int c = kk * 4 + (lane >> 4);
                bv[ni] = *(const f16x8*)(BsB + row * 128 + ((c ^ (row & 7)) << 4));
            }
#pragma unroll
            for (int mi = 0; mi < 4; ++mi)
#pragma unroll
                for (int ni = 0; ni < 4; ++ni)
                    acc[mi][ni] = __builtin_amdgcn_mfma_f32_16x16x32_f16(av[mi], bv[ni], acc[mi][ni], 0, 0, 0);
        }
    }

    // ---- epilogue: transpose each 16x16 fragment via per-wave LDS scratch ----
    __syncthreads();   // all waves done reading As/Bs
    float* sc = (float*)lds + wid * 1296;   // 4 regions of 324 floats (16 rows * 20 + pad)
    int bl = lane & 15, oi = lane >> 4;
    int o = nx * 8 + wc * 4 + oi;
    float biasv = bias[o];

#pragma unroll
    for (int mi = 0; mi < 4; ++mi) {
#pragma unroll
        for (int ni = 0; ni < 4; ++ni)
#pragma unroll
            for (int r = 0; r < 4; ++r)
                sc[ni * 324 + ((lane >> 4) * 4 + r) * 20 + (lane & 15)] = acc[mi][ni][r];
        __asm__ volatile("s_waitcnt lgkmcnt(0)" ::: "memory");

        float4 cnA = *(const float4*)(sc + oi * 324 + bl * 20 + 0);
        float4 cnB = *(const float4*)(sc + oi * 324 + bl * 20 + 4);
        float4 cdA = *(const float4*)(sc + oi * 324 + bl * 20 + 8);
        float4 cdB = *(const float4*)(sc + oi * 324 + bl * 20 + 12);
        float cn[8] = {cnA.x, cnA.y, cnA.z, cnA.w, cnB.x, cnB.y, cnB.z, cnB.w};
        float cd[8] = {cdA.x, cdA.y, cdA.z, cdA.w, cdB.x, cdB.y, cdB.z, cdB.w};

        int b = b0 + wr * 64 + mi * 16 + bl;
        float basev = basebuf[(size_t)b * FOUT + o];
        bool empty = cnts[b] > 0;

        float mix = 0.f, num0 = 0.f;
#pragma unroll
        for (int m = 0; m < 8; ++m) {
            float num = basev + cn[m] + biasv;
            if (m == 0) num0 = num;
            float den = sqrtf(fmaxf(cd[m], 0.f));
            float z = num / (den + 1e-9f);
            float pdf = 0.3989422804014327f * expf(-0.5f * z * z);
            float cdf = 0.5f * (1.0f + erff(z * 0.70710678118654752f));
            mix = fmaf(swv[m], den * (pdf + z * cdf), mix);
        }
        out[(size_t)b * FOUT + o] = empty ? mix : fmaxf(num0, 0.f);
    }
}

extern "C" void kernel_launch(void* const* d_in, const int* in_sizes, int n_in,
                              void* d_out, int out_size, void* d_ws, size_t ws_size,
                              hipStream_t stream) {
    const float* x        = (const float*)d_in[0];
    const float* W        = (const float*)d_in[1];
    const float* bvec     = (const float*)d_in[2];
    const float* mean_p   = (const float*)d_in[3];
    const float* log_std2 = (const float*)d_in[4];
    const float* lw       = (const float*)d_in[5];
    float* out = (float*)d_out;

    char* wsb = (char*)d_ws;
    float*     wsf  = (float*)wsb;                    // sw at [0..7]
    int*       cnts = (int*)(wsb + WSB_CNT);
    float*     base = (float*)(wsb + WSB_BASE);
    _Float16*  xch  = (_Float16*)(wsb + WSB_XCH);
    _Float16*  msk  = (_Float16*)(wsb + WSB_MSK);
    _Float16*  Wh   = (_Float16*)(wsb + WSB_WH);
    _Float16*  bct  = (_Float16*)(wsb + WSB_BCT);

    prep_w  <<<1025, 256, 0, stream>>>(W, lw, wsf, Wh);
    prep_bct<<<B_ROWS / 4, 256, 0, stream>>>(W, mean_p, log_std2, bct);
    prep_rows<<<B_ROWS / 4, 256, 0, stream>>>(x, xch, msk, cnts);
    gemm_base<<<dim3(FOUT / 64, B_ROWS / 128), 256, 0, stream>>>(xch, Wh, base);
    gmm_fused<<<(B_ROWS / 128) * (8192 / 128), 256, 0, stream>>>(msk, bct, wsf, cnts, base, bvec, out);
}

// Round 4
// 125.569 us; speedup vs baseline: 4.2595x; 1.5796x over previous
//
#include <hip/hip_runtime.h>
#include <math.h>

typedef __attribute__((ext_vector_type(8))) short short8;
typedef __attribute__((ext_vector_type(8))) _Float16 f16x8;
typedef __attribute__((ext_vector_type(4))) float floatx4;

#define B_ROWS 8192
#define FIN    512
#define FOUT   512

// ---- workspace byte offsets ----
#define WSB_SW   0UL         // 8 floats
#define WSB_CNT  64UL        // 8192 int
#define WSB_BASE 65536UL     // 8192*512 fp32
#define WSB_XCH  16842752UL  // 8192*512 f16 cleaned x
#define WSB_MSK  25231360UL  // 8192*512 f16 mask (1.0/0.0)
#define WSB_WH   33619968UL  // 512*512 f16 W [o][f]
#define WSB_BCT  34144256UL  // 8192*512 f16 BcT[n=o*16+t][f]

__device__ __forceinline__ void gl2lds16(const void* g, void* l) {
    __builtin_amdgcn_global_load_lds((const __attribute__((address_space(1))) void*)g,
                                     (__attribute__((address_space(3))) void*)l,
                                     16, 0, 0);
}

__device__ __forceinline__ float frcp(float x) { float r; asm("v_rcp_f32 %0, %1" : "=v"(r) : "v"(x)); return r; }
__device__ __forceinline__ float fsqrt(float x){ float r; asm("v_sqrt_f32 %0, %1" : "=v"(r) : "v"(x)); return r; }
__device__ __forceinline__ float fexp2(float x){ float r; asm("v_exp_f32 %0, %1" : "=v"(r) : "v"(x)); return r; }

// ---------------- prep: W f16 + softmax ----------------
__global__ __launch_bounds__(256) void prep_w(const float* __restrict__ W,
                                              const float* __restrict__ lw,
                                              float* __restrict__ wsf,
                                              _Float16* __restrict__ Wh) {
    int blk = blockIdx.x, tid = threadIdx.x;
    if (blk < 1024) {
        int idx = blk * 256 + tid;
        Wh[idx] = (_Float16)W[idx];
    } else if (tid == 0) {
        float mx = lw[0];
        for (int m = 1; m < 8; ++m) mx = fmaxf(mx, lw[m]);
        float e[8]; float s = 0.f;
        for (int m = 0; m < 8; ++m) { e[m] = expf(lw[m] - mx); s += e[m]; }
        for (int m = 0; m < 8; ++m) wsf[m] = e[m] / s;
    }
}

// ---------------- prep: BcT[n][f], n = o*16+t ----------------
__global__ __launch_bounds__(256) void prep_bct(const float* __restrict__ W,
                                                const float* __restrict__ mean_p,
                                                const float* __restrict__ ls2,
                                                _Float16* __restrict__ bct) {
    int tid = threadIdx.x;
    int n  = blockIdx.x * 4 + (tid >> 6);
    int fc = (tid & 63) << 3;
    int o = n >> 4, t = n & 15;
    const float* wp = W + (size_t)o * FIN + fc;
    f16x8 hv;
    if (t < 8) {
        const float* mp = mean_p + (size_t)t * FIN + fc;
#pragma unroll
        for (int j = 0; j < 8; ++j) hv[j] = (_Float16)(mp[j] * wp[j]);
    } else {
        const float* lp = ls2 + (size_t)(t - 8) * FIN + fc;
#pragma unroll
        for (int j = 0; j < 8; ++j) hv[j] = (_Float16)(expf(lp[j]) * wp[j] * wp[j]);
    }
    *(f16x8*)(bct + (size_t)n * FIN + fc) = hv;
}

// ---------------- prep: cleaned x f16 + mask f16 + counts ----------------
__global__ __launch_bounds__(256) void prep_rows(const float* __restrict__ x,
                                                 _Float16* __restrict__ xch,
                                                 _Float16* __restrict__ msk,
                                                 int* __restrict__ cnts) {
    int tid = threadIdx.x, lane = tid & 63, wid = tid >> 6;
    int row = blockIdx.x * 4 + wid;
    const float* xr = x + (size_t)row * FIN;
    int cnt = 0;
#pragma unroll
    for (int c = 0; c < FIN / 64; ++c) {
        float v = xr[c * 64 + lane];
        bool isn = (v != v);
        cnt += (int)__popcll(__ballot(isn));
        xch[(size_t)row * FIN + c * 64 + lane] = (_Float16)(isn ? 0.f : v);
        msk[(size_t)row * FIN + c * 64 + lane] = (_Float16)(isn ? 1.f : 0.f);
    }
    if (lane == 0) cnts[row] = cnt;
}

// ---------------- base GEMM: base[b,o] = sum_f xch[b,f]*Wh[o,f] (f16 MFMA) ----------------
__global__ __launch_bounds__(256) void gemm_base(const _Float16* __restrict__ xch,
                                                 const _Float16* __restrict__ Wh,
                                                 float* __restrict__ base) {
    __shared__ short As[128 * 64];
    __shared__ short Bs[64 * 64];
    int tid = threadIdx.x, lane = tid & 63, wid = tid >> 6;
    int wr = wid >> 1, wc = wid & 1;
    int bb0 = blockIdx.y * 128;
    int ob0 = blockIdx.x * 64;

    floatx4 acc[4][2];
#pragma unroll
    for (int mi = 0; mi < 4; ++mi)
#pragma unroll
        for (int ni = 0; ni < 2; ++ni) acc[mi][ni] = (floatx4){0.f, 0.f, 0.f, 0.f};

    for (int ks = 0; ks < FIN; ks += 64) {
        __syncthreads();
#pragma unroll
        for (int i = 0; i < 4; ++i) {
            int cid = i * 256 + tid, row = cid >> 3, c = cid & 7;
            short8 v = *(const short8*)((const short*)xch + (((size_t)(bb0 + row)) << 9) + ks + c * 8);
            *(short8*)(&As[row * 64 + ((c ^ (row & 7)) << 3)]) = v;
        }
#pragma unroll
        for (int i = 0; i < 2; ++i) {
            int cid = i * 256 + tid, row = cid >> 3, c = cid & 7;
            short8 v = *(const short8*)((const short*)Wh + (((size_t)(ob0 + row)) << 9) + ks + c * 8);
            *(short8*)(&Bs[row * 64 + ((c ^ (row & 7)) << 3)]) = v;
        }
        __syncthreads();
#pragma unroll
        for (int kk = 0; kk < 2; ++kk) {
            f16x8 av[4], bv[2];
#pragma unroll
            for (int mi = 0; mi < 4; ++mi) {
                int row = wr * 64 + mi * 16 + (lane & 15);
                int c = kk * 4 + (lane >> 4);
                av[mi] = *(const f16x8*)(&As[row * 64 + ((c ^ (row & 7)) << 3)]);
            }
#pragma unroll
            for (int ni = 0; ni < 2; ++ni) {
                int row = wc * 32 + ni * 16 + (lane & 15);
                int c = kk * 4 + (lane >> 4);
                bv[ni] = *(const f16x8*)(&Bs[row * 64 + ((c ^ (row & 7)) << 3)]);
            }
#pragma unroll
            for (int mi = 0; mi < 4; ++mi)
#pragma unroll
                for (int ni = 0; ni < 2; ++ni)
                    acc[mi][ni] = __builtin_amdgcn_mfma_f32_16x16x32_f16(av[mi], bv[ni], acc[mi][ni], 0, 0, 0);
        }
    }
#pragma unroll
    for (int mi = 0; mi < 4; ++mi)
#pragma unroll
        for (int ni = 0; ni < 2; ++ni)
#pragma unroll
            for (int r = 0; r < 4; ++r) {
                int row = bb0 + wr * 64 + mi * 16 + (lane >> 4) * 4 + r;
                int col = ob0 + wc * 32 + ni * 16 + (lane & 15);
                base[(size_t)row * FOUT + col] = acc[mi][ni][r];
            }
}

// ---------------- fused mask-GEMM + epilogue ----------------
// C[b, n=o*16+t] = sum_f mask[b,f] * BcT[n,f]; tile 128x128, BK=64, dbuf prefetch
__global__ __launch_bounds__(256) void gmm_fused(const _Float16* __restrict__ msk,
                                                 const _Float16* __restrict__ bct,
                                                 const float* __restrict__ wsf,
                                                 const int* __restrict__ cnts,
                                                 const float* __restrict__ basebuf,
                                                 const float* __restrict__ bias,
                                                 float* __restrict__ out) {
    __shared__ char lds[65536];   // 2 x (A 16KB + B 16KB)

    int tid = threadIdx.x, lane = tid & 63, wid = tid >> 6;
    int wr = wid >> 1, wc = wid & 1;

    // 8x8 grouped ordering for L2 locality
    int id = blockIdx.x, gid = id >> 6, wi = id & 63;
    int my = (gid >> 3) * 8 + (wi >> 3);
    int nx = (gid & 7) * 8 + (wi & 7);
    int b0 = my * 128, n0 = nx * 128;

    const char* mB = (const char*)msk;
    const char* bB = (const char*)bct;

    float swv[8];
#pragma unroll
    for (int m = 0; m < 8; ++m) swv[m] = wsf[m];

    floatx4 acc[4][4];
#pragma unroll
    for (int mi = 0; mi < 4; ++mi)
#pragma unroll
        for (int ni = 0; ni < 4; ++ni) acc[mi][ni] = (floatx4){0.f, 0.f, 0.f, 0.f};

    const int srow = (wid * 4 + 0);   // staging row-groups wid*4 .. wid*4+3

#define STAGE(BUF, KS)                                                              \
    {                                                                               \
        char* AsB_ = lds + (BUF) * 32768;                                           \
        char* BsB_ = AsB_ + 16384;                                                  \
        _Pragma("unroll")                                                           \
        for (int j = 0; j < 4; ++j) {                                               \
            int rg = srow + j;                                                      \
            int row = rg * 8 + (lane >> 3);                                         \
            int c = lane & 7;                                                       \
            size_t goff = (size_t)row * 1024 + (KS) * 2 + ((c ^ (row & 7)) << 4);   \
            gl2lds16(mB + (size_t)b0 * 1024 + goff, AsB_ + rg * 1024);              \
            gl2lds16(bB + (size_t)n0 * 1024 + goff, BsB_ + rg * 1024);              \
        }                                                                           \
    }

    STAGE(0, 0);
    __syncthreads();          // drains vmcnt(0): tile 0 ready

#pragma unroll
    for (int t = 0; t < 8; ++t) {
        const int cur = t & 1;
        if (t < 7) STAGE(cur ^ 1, (t + 1) * 64);     // prefetch flies under compute
        const char* AsB = lds + cur * 32768;
        const char* BsB = AsB + 16384;
#pragma unroll
        for (int kk = 0; kk < 2; ++kk) {
            f16x8 av[4], bv[4];
#pragma unroll
            for (int mi = 0; mi < 4; ++mi) {
                int row = wr * 64 + mi * 16 + (lane & 15);
                int c = kk * 4 + (lane >> 4);
                av[mi] = *(const f16x8*)(AsB + row * 128 + ((c ^ (row & 7)) << 4));
            }
#pragma unroll
            for (int ni = 0; ni < 4; ++ni) {
                int row = wc * 64 + ni * 16 + (lane & 15);
                int c = kk * 4 + (lane >> 4);
                bv[ni] = *(const f16x8*)(BsB + row * 128 + ((c ^ (row & 7)) << 4));
            }
#pragma unroll
            for (int mi = 0; mi < 4; ++mi)
#pragma unroll
                for (int ni = 0; ni < 4; ++ni)
                    acc[mi][ni] = __builtin_amdgcn_mfma_f32_16x16x32_f16(av[mi], bv[ni], acc[mi][ni], 0, 0, 0);
        }
        __syncthreads();      // all waves done with buf[cur]; prefetch into buf[cur^1] landed
    }

    // ---- epilogue: transpose each 16x16 fragment via per-wave LDS scratch ----
    float* sc = (float*)lds + wid * 1296;   // 4 regions of 324 floats (16 rows * 20 + pad)
    int bl = lane & 15, oi = lane >> 4;
    int o = nx * 8 + wc * 4 + oi;
    float biasv = bias[o];

#pragma unroll
    for (int mi = 0; mi < 4; ++mi) {
#pragma unroll
        for (int ni = 0; ni < 4; ++ni)
#pragma unroll
            for (int r = 0; r < 4; ++r)
                sc[ni * 324 + (oi * 4 + r) * 20 + bl] = acc[mi][ni][r];
        __asm__ volatile("s_waitcnt lgkmcnt(0)" ::: "memory");

        float4 cnA = *(const float4*)(sc + oi * 324 + bl * 20 + 0);
        float4 cnB = *(const float4*)(sc + oi * 324 + bl * 20 + 4);
        float4 cdA = *(const float4*)(sc + oi * 324 + bl * 20 + 8);
        float4 cdB = *(const float4*)(sc + oi * 324 + bl * 20 + 12);
        float cn[8] = {cnA.x, cnA.y, cnA.z, cnA.w, cnB.x, cnB.y, cnB.z, cnB.w};
        float cd[8] = {cdA.x, cdA.y, cdA.z, cdA.w, cdB.x, cdB.y, cdB.z, cdB.w};

        int b = b0 + wr * 64 + mi * 16 + bl;
        float basev = basebuf[(size_t)b * FOUT + o];
        bool empty = cnts[b] > 0;

        float mix = 0.f, num0 = 0.f;
#pragma unroll
        for (int m = 0; m < 8; ++m) {
            float num = basev + cn[m] + biasv;
            if (m == 0) num0 = num;
            float den = fsqrt(fmaxf(cd[m], 0.f));
            float z   = num * frcp(den + 1e-9f);
            // E = exp(-z^2/2) shared by pdf and A&S erf (x = z/sqrt2 -> e^{-x^2} = E)
            float E   = fexp2(z * z * -0.72134752044448170f);
            float pdf = 0.3989422804014327f * E;
            float t1  = frcp(fmaf(0.2316419f * 0.70710678f, fabsf(z), 1.0f));
            float h   = fmaf(t1, 1.061405429f, -1.453152027f);
            h = fmaf(t1, h, 1.421413741f);
            h = fmaf(t1, h, -0.284496736f);
            h = fmaf(t1, h, 0.254829592f);
            float q   = 0.5f * (t1 * h) * E;          // 0.5*(1-erf(|x|))
            float cdf = (z >= 0.f) ? (1.0f - q) : q;
            float nr  = fmaf(z, cdf, pdf);
            mix = fmaf(swv[m], den * nr, mix);
        }
        out[(size_t)b * FOUT + o] = empty ? mix : fmaxf(num0, 0.f);
    }
#undef STAGE
}

extern "C" void kernel_launch(void* const* d_in, const int* in_sizes, int n_in,
                              void* d_out, int out_size, void* d_ws, size_t ws_size,
                              hipStream_t stream) {
    const float* x        = (const float*)d_in[0];
    const float* W        = (const float*)d_in[1];
    const float* bvec     = (const float*)d_in[2];
    const float* mean_p   = (const float*)d_in[3];
    const float* log_std2 = (const float*)d_in[4];
    const float* lw       = (const float*)d_in[5];
    float* out = (float*)d_out;

    char* wsb = (char*)d_ws;
    float*     wsf  = (float*)wsb;
    int*       cnts = (int*)(wsb + WSB_CNT);
    float*     base = (float*)(wsb + WSB_BASE);
    _Float16*  xch  = (_Float16*)(wsb + WSB_XCH);
    _Float16*  msk  = (_Float16*)(wsb + WSB_MSK);
    _Float16*  Wh   = (_Float16*)(wsb + WSB_WH);
    _Float16*  bct  = (_Float16*)(wsb + WSB_BCT);

    prep_w  <<<1025, 256, 0, stream>>>(W, lw, wsf, Wh);
    prep_bct<<<B_ROWS / 4, 256, 0, stream>>>(W, mean_p, log_std2, bct);
    prep_rows<<<B_ROWS / 4, 256, 0, stream>>>(x, xch, msk, cnts);
    gemm_base<<<dim3(FOUT / 64, B_ROWS / 128), 256, 0, stream>>>(xch, Wh, base);
    gmm_fused<<<(B_ROWS / 128) * (8192 / 128), 256, 0, stream>>>(msk, bct, wsf, cnts, base, bvec, out);
}

// Round 5
// 120.029 us; speedup vs baseline: 4.4561x; 1.0462x over previous
//
#include <hip/hip_runtime.h>
#include <math.h>

typedef __attribute__((ext_vector_type(8))) short short8;
typedef __attribute__((ext_vector_type(8))) _Float16 f16x8;
typedef __attribute__((ext_vector_type(4))) float floatx4;

#define B_ROWS 8192
#define FIN    512
#define FOUT   512

// ---- workspace byte offsets ----
#define WSB_SW   0UL         // 8 floats
#define WSB_CNT  64UL        // 8192 int (any-NaN flag per row)
#define WSB_BASE 65536UL     // 8192*512 fp32
#define WSB_XCH  16842752UL  // 8192*512 f16 cleaned x
#define WSB_MSK  25231360UL  // 8192*512 f16 mask (1.0/0.0)
#define WSB_WH   33619968UL  // 512*512 f16 W [o][f]
#define WSB_BCT  34144256UL  // 8192*512 f16 BcT[n=o*16+t][f]

__device__ __forceinline__ void gl2lds16(const void* g, void* l) {
    __builtin_amdgcn_global_load_lds((const __attribute__((address_space(1))) void*)g,
                                     (__attribute__((address_space(3))) void*)l,
                                     16, 0, 0);
}

__device__ __forceinline__ float frcp(float x) { float r; asm("v_rcp_f32 %0, %1" : "=v"(r) : "v"(x)); return r; }
__device__ __forceinline__ float fsqrt(float x){ float r; asm("v_sqrt_f32 %0, %1" : "=v"(r) : "v"(x)); return r; }
__device__ __forceinline__ float fexp2(float x){ float r; asm("v_exp_f32 %0, %1" : "=v"(r) : "v"(x)); return r; }

// ---------------- prep: BcT[n][f] (n=o*16+t) + Wh fold ----------------
__global__ __launch_bounds__(256) void prep_bct(const float* __restrict__ W,
                                                const float* __restrict__ mean_p,
                                                const float* __restrict__ ls2,
                                                _Float16* __restrict__ bct,
                                                _Float16* __restrict__ Wh) {
    int tid = threadIdx.x;
    int n  = blockIdx.x * 4 + (tid >> 6);
    int fc = (tid & 63) << 3;
    int o = n >> 4, t = n & 15;
    const float* wp = W + (size_t)o * FIN + fc;
    f16x8 hv;
    if (t < 8) {
        const float* mp = mean_p + (size_t)t * FIN + fc;
#pragma unroll
        for (int j = 0; j < 8; ++j) hv[j] = (_Float16)(mp[j] * wp[j]);
        if (t == 0) {
            f16x8 wv;
#pragma unroll
            for (int j = 0; j < 8; ++j) wv[j] = (_Float16)wp[j];
            *(f16x8*)(Wh + (size_t)o * FIN + fc) = wv;
        }
    } else {
        const float* lp = ls2 + (size_t)(t - 8) * FIN + fc;
#pragma unroll
        for (int j = 0; j < 8; ++j) hv[j] = (_Float16)(expf(lp[j]) * wp[j] * wp[j]);
    }
    *(f16x8*)(bct + (size_t)n * FIN + fc) = hv;
}

// ---------------- prep: cleaned x f16 + mask f16 + any-NaN flag + softmax ----------------
__global__ __launch_bounds__(256) void prep_rows(const float* __restrict__ x,
                                                 _Float16* __restrict__ xch,
                                                 _Float16* __restrict__ msk,
                                                 int* __restrict__ cnts,
                                                 const float* __restrict__ lw,
                                                 float* __restrict__ wsf) {
    int tid = threadIdx.x, lane = tid & 63, wid = tid >> 6;
    int row = blockIdx.x * 4 + wid;
    const float* xr = x + (size_t)row * FIN + lane * 8;
    float4 a = *(const float4*)xr;
    float4 b = *(const float4*)(xr + 4);
    float v[8] = {a.x, a.y, a.z, a.w, b.x, b.y, b.z, b.w};
    f16x8 xo, mo;
    bool anyn = false;
#pragma unroll
    for (int j = 0; j < 8; ++j) {
        bool isn = (v[j] != v[j]);
        anyn |= isn;
        xo[j] = (_Float16)(isn ? 0.f : v[j]);
        mo[j] = (_Float16)(isn ? 1.f : 0.f);
    }
    *(f16x8*)(xch + (size_t)row * FIN + lane * 8) = xo;
    *(f16x8*)(msk + (size_t)row * FIN + lane * 8) = mo;
    bool any = __any(anyn);
    if (lane == 0) cnts[row] = any ? 1 : 0;
    if (blockIdx.x == 0 && tid == 0) {
        float mx = lw[0];
        for (int m = 1; m < 8; ++m) mx = fmaxf(mx, lw[m]);
        float e[8]; float s = 0.f;
        for (int m = 0; m < 8; ++m) { e[m] = expf(lw[m] - mx); s += e[m]; }
        for (int m = 0; m < 8; ++m) wsf[m] = e[m] / s;
    }
}

// ---------------- base GEMM: base[b,o] = sum_f xch[b,f]*Wh[o,f] (f16 MFMA) ----------------
__global__ __launch_bounds__(256) void gemm_base(const _Float16* __restrict__ xch,
                                                 const _Float16* __restrict__ Wh,
                                                 float* __restrict__ base) {
    __shared__ short As[128 * 64];
    __shared__ short Bs[64 * 64];
    int tid = threadIdx.x, lane = tid & 63, wid = tid >> 6;
    int wr = wid >> 1, wc = wid & 1;
    int bb0 = blockIdx.y * 128;
    int ob0 = blockIdx.x * 64;

    floatx4 acc[4][2];
#pragma unroll
    for (int mi = 0; mi < 4; ++mi)
#pragma unroll
        for (int ni = 0; ni < 2; ++ni) acc[mi][ni] = (floatx4){0.f, 0.f, 0.f, 0.f};

    for (int ks = 0; ks < FIN; ks += 64) {
        __syncthreads();
#pragma unroll
        for (int i = 0; i < 4; ++i) {
            int cid = i * 256 + tid, row = cid >> 3, c = cid & 7;
            short8 v = *(const short8*)((const short*)xch + (((size_t)(bb0 + row)) << 9) + ks + c * 8);
            *(short8*)(&As[row * 64 + ((c ^ (row & 7)) << 3)]) = v;
        }
#pragma unroll
        for (int i = 0; i < 2; ++i) {
            int cid = i * 256 + tid, row = cid >> 3, c = cid & 7;
            short8 v = *(const short8*)((const short*)Wh + (((size_t)(ob0 + row)) << 9) + ks + c * 8);
            *(short8*)(&Bs[row * 64 + ((c ^ (row & 7)) << 3)]) = v;
        }
        __syncthreads();
#pragma unroll
        for (int kk = 0; kk < 2; ++kk) {
            f16x8 av[4], bv[2];
#pragma unroll
            for (int mi = 0; mi < 4; ++mi) {
                int row = wr * 64 + mi * 16 + (lane & 15);
                int c = kk * 4 + (lane >> 4);
                av[mi] = *(const f16x8*)(&As[row * 64 + ((c ^ (row & 7)) << 3)]);
            }
#pragma unroll
            for (int ni = 0; ni < 2; ++ni) {
                int row = wc * 32 + ni * 16 + (lane & 15);
                int c = kk * 4 + (lane >> 4);
                bv[ni] = *(const f16x8*)(&Bs[row * 64 + ((c ^ (row & 7)) << 3)]);
            }
#pragma unroll
            for (int mi = 0; mi < 4; ++mi)
#pragma unroll
                for (int ni = 0; ni < 2; ++ni)
                    acc[mi][ni] = __builtin_amdgcn_mfma_f32_16x16x32_f16(av[mi], bv[ni], acc[mi][ni], 0, 0, 0);
        }
    }
#pragma unroll
    for (int mi = 0; mi < 4; ++mi)
#pragma unroll
        for (int ni = 0; ni < 2; ++ni)
#pragma unroll
            for (int r = 0; r < 4; ++r) {
                int row = bb0 + wr * 64 + mi * 16 + (lane >> 4) * 4 + r;
                int col = ob0 + wc * 32 + ni * 16 + (lane & 15);
                base[(size_t)row * FOUT + col] = acc[mi][ni][r];
            }
}

// ---------------- fused mask-GEMM + epilogue ----------------
// C[b, n=o*16+t] = sum_f mask[b,f] * BcT[n,f]
// tile 128x128, BK=32, 4 LDS buffers (16KB each), depth-2 counted vmcnt
__global__ __launch_bounds__(256) void gmm_fused(const _Float16* __restrict__ msk,
                                                 const _Float16* __restrict__ bct,
                                                 const float* __restrict__ wsf,
                                                 const int* __restrict__ cnts,
                                                 const float* __restrict__ basebuf,
                                                 const float* __restrict__ bias,
                                                 float* __restrict__ out) {
    __shared__ char lds[65536];   // 4 x (A 8KB + B 8KB)

    int tid = threadIdx.x, lane = tid & 63, wid = tid >> 6;
    int wr = wid >> 1, wc = wid & 1;

    // 8x8 grouped ordering for L2 locality
    int id = blockIdx.x, gid = id >> 6, wi = id & 63;
    int my = (gid >> 3) * 8 + (wi >> 3);
    int nx = (gid & 7) * 8 + (wi & 7);
    int b0 = my * 128, n0 = nx * 128;

    const char* mB = (const char*)msk;
    const char* bB = (const char*)bct;

    floatx4 acc[4][4];
#pragma unroll
    for (int mi = 0; mi < 4; ++mi)
#pragma unroll
        for (int ni = 0; ni < 4; ++ni) acc[mi][ni] = (floatx4){0.f, 0.f, 0.f, 0.f};

    // stage one BK=32 tile T into buffer BUF: per wave 4 gl2lds (2 A-chunks + 2 B-chunks)
#define STAGE(BUF, T)                                                               \
    {                                                                               \
        char* Ab_ = lds + (BUF) * 16384;                                            \
        char* Bb_ = Ab_ + 8192;                                                     \
        _Pragma("unroll")                                                           \
        for (int q = 0; q < 2; ++q) {                                               \
            int k = wid * 2 + q;                                                    \
            int row = k * 16 + (lane >> 2);                                         \
            size_t go = (size_t)row * 1024 + (size_t)(T) * 64 +                     \
                        (size_t)((((lane & 3) ^ ((row >> 1) & 3))) << 4);           \
            gl2lds16(mB + (size_t)b0 * 1024 + go, Ab_ + k * 1024);                  \
            gl2lds16(bB + (size_t)n0 * 1024 + go, Bb_ + k * 1024);                  \
        }                                                                           \
    }

    STAGE(0, 0); STAGE(1, 1); STAGE(2, 2);   // 12 loads in flight per wave

#pragma unroll
    for (int t = 0; t < 16; ++t) {
        // wait: own tile-t loads done; tiles t+1,t+2 (8 loads) stay in flight
        if (t <= 13)      asm volatile("s_waitcnt vmcnt(8)" ::: "memory");
        else if (t == 14) asm volatile("s_waitcnt vmcnt(4)" ::: "memory");
        else              asm volatile("s_waitcnt vmcnt(0)" ::: "memory");
        __builtin_amdgcn_s_barrier();        // all waves: tile-t staged; tile t-1 reads done
        asm volatile("" ::: "memory");       // fence: keep ds_reads/STAGE below barrier
        if (t + 3 < 16) STAGE((t + 3) & 3, t + 3);

        const char* Ab = lds + (t & 3) * 16384;
        const char* Bb = Ab + 8192;
        int c = lane >> 4;
        f16x8 av[4], bv[4];
#pragma unroll
        for (int mi = 0; mi < 4; ++mi) {
            int row = wr * 64 + mi * 16 + (lane & 15);
            av[mi] = *(const f16x8*)(Ab + row * 64 + ((c ^ ((row >> 1) & 3)) << 4));
        }
#pragma unroll
        for (int ni = 0; ni < 4; ++ni) {
            int row = wc * 64 + ni * 16 + (lane & 15);
            bv[ni] = *(const f16x8*)(Bb + row * 64 + ((c ^ ((row >> 1) & 3)) << 4));
        }
        __builtin_amdgcn_s_setprio(1);
#pragma unroll
        for (int mi = 0; mi < 4; ++mi)
#pragma unroll
            for (int ni = 0; ni < 4; ++ni)
                acc[mi][ni] = __builtin_amdgcn_mfma_f32_16x16x32_f16(av[mi], bv[ni], acc[mi][ni], 0, 0, 0);
        __builtin_amdgcn_s_setprio(0);
    }
#undef STAGE

    __syncthreads();   // full drain before LDS reuse as epilogue scratch

    float swv[8];
#pragma unroll
    for (int m = 0; m < 8; ++m) swv[m] = wsf[m];

    // epilogue: transpose each 16x16 fragment via per-wave LDS scratch
    float* sc = (float*)lds + wid * 1296;   // 4 regions of 324 floats (16 rows * 20 + pad)
    int bl = lane & 15, oi = lane >> 4;
    int o = nx * 8 + wc * 4 + oi;
    float biasv = bias[o];

#pragma unroll
    for (int mi = 0; mi < 4; ++mi) {
#pragma unroll
        for (int ni = 0; ni < 4; ++ni)
#pragma unroll
            for (int r = 0; r < 4; ++r)
                sc[ni * 324 + (oi * 4 + r) * 20 + bl] = acc[mi][ni][r];
        __asm__ volatile("s_waitcnt lgkmcnt(0)" ::: "memory");

        float4 cnA = *(const float4*)(sc + oi * 324 + bl * 20 + 0);
        float4 cnB = *(const float4*)(sc + oi * 324 + bl * 20 + 4);
        float4 cdA = *(const float4*)(sc + oi * 324 + bl * 20 + 8);
        float4 cdB = *(const float4*)(sc + oi * 324 + bl * 20 + 12);
        float cn[8] = {cnA.x, cnA.y, cnA.z, cnA.w, cnB.x, cnB.y, cnB.z, cnB.w};
        float cd[8] = {cdA.x, cdA.y, cdA.z, cdA.w, cdB.x, cdB.y, cdB.z, cdB.w};

        int b = b0 + wr * 64 + mi * 16 + bl;
        float basev = basebuf[(size_t)b * FOUT + o];
        float K0 = basev + biasv;
        bool empty = cnts[b] > 0;

        float mix = 0.f, num0 = 0.f;
#pragma unroll
        for (int m = 0; m < 8; ++m) {
            float num = K0 + cn[m];
            if (m == 0) num0 = num;
            float den = fsqrt(fmaxf(cd[m], 0.f));
            float z   = num * frcp(den + 1e-9f);
            float az  = fabsf(z);
            float E   = fexp2(z * z * -0.72134752044448170f);   // exp(-z^2/2)
            float pdf = 0.3989422804014327f * E;
            // Q(az) = 1-Phi(az) via A&S 26.2.17: t = 1/(1+0.2316419*az)
            float t1  = frcp(fmaf(0.2316419f, az, 1.0f));
            float h   = fmaf(t1, 1.061405429f, -1.453152027f);
            h = fmaf(t1, h, 1.421413741f);
            h = fmaf(t1, h, -0.284496736f);
            h = fmaf(t1, h, 0.254829592f);
            float Q   = 0.5f * (t1 * h) * E;
            // g(z) = pdf + max(z,0) - az*Q ; contribution = sw * den * g
            float g   = fmaf(-az, Q, pdf + fmaxf(z, 0.f));
            mix = fmaf(swv[m], den * g, mix);
        }
        out[(size_t)b * FOUT + o] = empty ? mix : fmaxf(num0, 0.f);
    }
}

extern "C" void kernel_launch(void* const* d_in, const int* in_sizes, int n_in,
                              void* d_out, int out_size, void* d_ws, size_t ws_size,
                              hipStream_t stream) {
    const float* x        = (const float*)d_in[0];
    const float* W        = (const float*)d_in[1];
    const float* bvec     = (const float*)d_in[2];
    const float* mean_p   = (const float*)d_in[3];
    const float* log_std2 = (const float*)d_in[4];
    const float* lw       = (const float*)d_in[5];
    float* out = (float*)d_out;

    char* wsb = (char*)d_ws;
    float*     wsf  = (float*)wsb;
    int*       cnts = (int*)(wsb + WSB_CNT);
    float*     base = (float*)(wsb + WSB_BASE);
    _Float16*  xch  = (_Float16*)(wsb + WSB_XCH);
    _Float16*  msk  = (_Float16*)(wsb + WSB_MSK);
    _Float16*  Wh   = (_Float16*)(wsb + WSB_WH);
    _Float16*  bct  = (_Float16*)(wsb + WSB_BCT);

    prep_bct <<<B_ROWS / 4, 256, 0, stream>>>(W, mean_p, log_std2, bct, Wh);
    prep_rows<<<B_ROWS / 4, 256, 0, stream>>>(x, xch, msk, cnts, lw, wsf);
    gemm_base<<<dim3(FOUT / 64, B_ROWS / 128), 256, 0, stream>>>(xch, Wh, base);
    gmm_fused<<<(B_ROWS / 128) * (8192 / 128), 256, 0, stream>>>(msk, bct, wsf, cnts, base, bvec, out);
}

// Round 6
// 102.836 us; speedup vs baseline: 5.2011x; 1.1672x over previous
//
#include <hip/hip_runtime.h>
#include <math.h>

typedef __attribute__((ext_vector_type(8))) short short8;
typedef __attribute__((ext_vector_type(8))) _Float16 f16x8;
typedef __attribute__((ext_vector_type(4))) float floatx4;

#define B_ROWS 8192
#define FIN    512
#define FOUT   512

// ---- workspace byte offsets ----
#define WSB_SW   0UL         // 8 floats
#define WSB_CNT  64UL        // 8192 int (any-NaN flag per row)
#define WSB_BASE 65536UL     // 8192*512 f16 base GEMM result
#define WSB_XCH  16842752UL  // 8192*512 f16 cleaned x
#define WSB_MSK  25231360UL  // 8192*512 f16 mask (1.0/0.0)
#define WSB_WH   33619968UL  // 512*512 f16 W [o][f]
#define WSB_BCT  34144256UL  // 8192*512 f16 BcT[n=o*16+t][f]

__device__ __forceinline__ void gl2lds16(const void* g, void* l) {
    __builtin_amdgcn_global_load_lds((const __attribute__((address_space(1))) void*)g,
                                     (__attribute__((address_space(3))) void*)l,
                                     16, 0, 0);
}

__device__ __forceinline__ float frcp(float x) { float r; asm("v_rcp_f32 %0, %1" : "=v"(r) : "v"(x)); return r; }
__device__ __forceinline__ float frsq(float x) { float r; asm("v_rsq_f32 %0, %1" : "=v"(r) : "v"(x)); return r; }
__device__ __forceinline__ float fexp2(float x){ float r; asm("v_exp_f32 %0, %1" : "=v"(r) : "v"(x)); return r; }

// ---------------- prep: BcT[n][f] (n=o*16+t) + Wh fold ----------------
__global__ __launch_bounds__(256) void prep_bct(const float* __restrict__ W,
                                                const float* __restrict__ mean_p,
                                                const float* __restrict__ ls2,
                                                _Float16* __restrict__ bct,
                                                _Float16* __restrict__ Wh) {
    int tid = threadIdx.x;
    int n  = blockIdx.x * 4 + (tid >> 6);
    int fc = (tid & 63) << 3;
    int o = n >> 4, t = n & 15;
    const float* wp = W + (size_t)o * FIN + fc;
    f16x8 hv;
    if (t < 8) {
        const float* mp = mean_p + (size_t)t * FIN + fc;
#pragma unroll
        for (int j = 0; j < 8; ++j) hv[j] = (_Float16)(mp[j] * wp[j]);
        if (t == 0) {
            f16x8 wv;
#pragma unroll
            for (int j = 0; j < 8; ++j) wv[j] = (_Float16)wp[j];
            *(f16x8*)(Wh + (size_t)o * FIN + fc) = wv;
        }
    } else {
        const float* lp = ls2 + (size_t)(t - 8) * FIN + fc;
#pragma unroll
        for (int j = 0; j < 8; ++j) hv[j] = (_Float16)(expf(lp[j]) * wp[j] * wp[j]);
    }
    *(f16x8*)(bct + (size_t)n * FIN + fc) = hv;
}

// ---------------- prep: cleaned x f16 + mask f16 + any-NaN flag + softmax ----------------
__global__ __launch_bounds__(256) void prep_rows(const float* __restrict__ x,
                                                 _Float16* __restrict__ xch,
                                                 _Float16* __restrict__ msk,
                                                 int* __restrict__ cnts,
                                                 const float* __restrict__ lw,
                                                 float* __restrict__ wsf) {
    int tid = threadIdx.x, lane = tid & 63, wid = tid >> 6;
    int row = blockIdx.x * 4 + wid;
    const float* xr = x + (size_t)row * FIN + lane * 8;
    float4 a = *(const float4*)xr;
    float4 b = *(const float4*)(xr + 4);
    float v[8] = {a.x, a.y, a.z, a.w, b.x, b.y, b.z, b.w};
    f16x8 xo, mo;
    bool anyn = false;
#pragma unroll
    for (int j = 0; j < 8; ++j) {
        bool isn = (v[j] != v[j]);
        anyn |= isn;
        xo[j] = (_Float16)(isn ? 0.f : v[j]);
        mo[j] = (_Float16)(isn ? 1.f : 0.f);
    }
    *(f16x8*)(xch + (size_t)row * FIN + lane * 8) = xo;
    *(f16x8*)(msk + (size_t)row * FIN + lane * 8) = mo;
    bool any = __any(anyn);
    if (lane == 0) cnts[row] = any ? 1 : 0;
    if (blockIdx.x == 0 && tid == 0) {
        float mx = lw[0];
        for (int m = 1; m < 8; ++m) mx = fmaxf(mx, lw[m]);
        float e[8]; float s = 0.f;
        for (int m = 0; m < 8; ++m) { e[m] = expf(lw[m] - mx); s += e[m]; }
        for (int m = 0; m < 8; ++m) wsf[m] = e[m] / s;
    }
}

// ---------------- base GEMM: base[b,o] = sum_f xch[b,f]*Wh[o,f] (f16 MFMA, f16 out) ----------------
__global__ __launch_bounds__(256) void gemm_base(const _Float16* __restrict__ xch,
                                                 const _Float16* __restrict__ Wh,
                                                 _Float16* __restrict__ base) {
    __shared__ short As[128 * 64];
    __shared__ short Bs[64 * 64];
    int tid = threadIdx.x, lane = tid & 63, wid = tid >> 6;
    int wr = wid >> 1, wc = wid & 1;
    int bb0 = blockIdx.y * 128;
    int ob0 = blockIdx.x * 64;

    floatx4 acc[4][2];
#pragma unroll
    for (int mi = 0; mi < 4; ++mi)
#pragma unroll
        for (int ni = 0; ni < 2; ++ni) acc[mi][ni] = (floatx4){0.f, 0.f, 0.f, 0.f};

    for (int ks = 0; ks < FIN; ks += 64) {
        __syncthreads();
#pragma unroll
        for (int i = 0; i < 4; ++i) {
            int cid = i * 256 + tid, row = cid >> 3, c = cid & 7;
            short8 v = *(const short8*)((const short*)xch + (((size_t)(bb0 + row)) << 9) + ks + c * 8);
            *(short8*)(&As[row * 64 + ((c ^ (row & 7)) << 3)]) = v;
        }
#pragma unroll
        for (int i = 0; i < 2; ++i) {
            int cid = i * 256 + tid, row = cid >> 3, c = cid & 7;
            short8 v = *(const short8*)((const short*)Wh + (((size_t)(ob0 + row)) << 9) + ks + c * 8);
            *(short8*)(&Bs[row * 64 + ((c ^ (row & 7)) << 3)]) = v;
        }
        __syncthreads();
#pragma unroll
        for (int kk = 0; kk < 2; ++kk) {
            f16x8 av[4], bv[2];
#pragma unroll
            for (int mi = 0; mi < 4; ++mi) {
                int row = wr * 64 + mi * 16 + (lane & 15);
                int c = kk * 4 + (lane >> 4);
                av[mi] = *(const f16x8*)(&As[row * 64 + ((c ^ (row & 7)) << 3)]);
            }
#pragma unroll
            for (int ni = 0; ni < 2; ++ni) {
                int row = wc * 32 + ni * 16 + (lane & 15);
                int c = kk * 4 + (lane >> 4);
                bv[ni] = *(const f16x8*)(&Bs[row * 64 + ((c ^ (row & 7)) << 3)]);
            }
#pragma unroll
            for (int mi = 0; mi < 4; ++mi)
#pragma unroll
                for (int ni = 0; ni < 2; ++ni)
                    acc[mi][ni] = __builtin_amdgcn_mfma_f32_16x16x32_f16(av[mi], bv[ni], acc[mi][ni], 0, 0, 0);
        }
    }
#pragma unroll
    for (int mi = 0; mi < 4; ++mi)
#pragma unroll
        for (int ni = 0; ni < 2; ++ni)
#pragma unroll
            for (int r = 0; r < 4; ++r) {
                int row = bb0 + wr * 64 + mi * 16 + (lane >> 4) * 4 + r;
                int col = ob0 + wc * 32 + ni * 16 + (lane & 15);
                base[(size_t)row * FOUT + col] = (_Float16)acc[mi][ni][r];
            }
}

// ---------------- fused mask-GEMM + epilogue ----------------
// C[b, n=o*16+t] = sum_f mask[b,f] * BcT[n,f]
// tile 256(M) x 128(N), BK=32, 8 waves (4m x 2n), 3 LDS buffers, counted vmcnt,
// all addressing hoisted out of the K-loop.
__global__ __launch_bounds__(512, 4) void gmm_fused(const _Float16* __restrict__ msk,
                                                    const _Float16* __restrict__ bct,
                                                    const float* __restrict__ wsf,
                                                    const int* __restrict__ cnts,
                                                    const _Float16* __restrict__ baseh,
                                                    const float* __restrict__ bias,
                                                    float* __restrict__ out) {
    __shared__ char lds[73728];   // 3 x (A 16KB + B 8KB)

    int tid = threadIdx.x, lane = tid & 63, wid = tid >> 6;
    int wr = wid >> 1, wc = wid & 1;        // 4 x 2 wave grid

    // 8x8 grouped ordering for L2 locality: my in [0,32), nx in [0,64)
    int id = blockIdx.x, gid = id >> 6, wi = id & 63;
    int my = (gid >> 3) * 8 + (wi >> 3);
    int nx = (gid & 7) * 8 + (wi & 7);
    int b0 = my * 256, n0 = nx * 128;

    const char* mB = (const char*)msk;
    const char* bB = (const char*)bct;

    // ---- hoisted staging addresses (per wave, computed once) ----
    // A: rows slot*16+(lane>>2), slot = q*8+wid (q=0,1); B: slot = wid
    int rA0 = (wid * 16) + (lane >> 2);
    int rA1 = ((8 + wid) * 16) + (lane >> 2);
    int rB  = rA0;
    const char* gA0 = mB + (size_t)(b0 + rA0) * 1024 + (size_t)((((lane & 3) ^ ((rA0 >> 1) & 3))) << 4);
    const char* gA1 = mB + (size_t)(b0 + rA1) * 1024 + (size_t)((((lane & 3) ^ ((rA1 >> 1) & 3))) << 4);
    const char* gB0 = bB + (size_t)(n0 + rB ) * 1024 + (size_t)((((lane & 3) ^ ((rB  >> 1) & 3))) << 4);
    char* lA0 = lds + wid * 1024;
    char* lA1 = lds + (8 + wid) * 1024;
    char* lB0 = lds + 16384 + wid * 1024;

    // ---- hoisted LDS read offsets (per lane, once) ----
    int offA[4], offB[4];
#pragma unroll
    for (int mi = 0; mi < 4; ++mi) {
        int row = wr * 64 + mi * 16 + (lane & 15);
        offA[mi] = row * 64 + (((lane >> 4) ^ ((row >> 1) & 3)) << 4);
    }
#pragma unroll
    for (int ni = 0; ni < 4; ++ni) {
        int row = wc * 64 + ni * 16 + (lane & 15);
        offB[ni] = 16384 + row * 64 + (((lane >> 4) ^ ((row >> 1) & 3)) << 4);
    }

    floatx4 acc[4][4];
#pragma unroll
    for (int mi = 0; mi < 4; ++mi)
#pragma unroll
        for (int ni = 0; ni < 4; ++ni) acc[mi][ni] = (floatx4){0.f, 0.f, 0.f, 0.f};

#define STAGE(T)                                             \
    {                                                        \
        const int bo_ = ((T) % 3) * 24576;                   \
        gl2lds16(gA0 + (T) * 64, lA0 + bo_);                 \
        gl2lds16(gA1 + (T) * 64, lA1 + bo_);                 \
        gl2lds16(gB0 + (T) * 64, lB0 + bo_);                 \
    }

    STAGE(0); STAGE(1);     // 6 loads in flight per wave

#pragma unroll
    for (int t = 0; t < 16; ++t) {
        if (t < 15) asm volatile("s_waitcnt vmcnt(3)" ::: "memory");   // tile t landed; t+1 in flight
        else        asm volatile("s_waitcnt vmcnt(0)" ::: "memory");
        __builtin_amdgcn_s_barrier();       // tile t staged by all; buf (t-1)%3 read-complete by all
        asm volatile("" ::: "memory");
        if (t + 2 < 16) STAGE(t + 2);       // into buf (t+2)%3 == (t-1)%3

        const int bo = (t % 3) * 24576;
        f16x8 av[4], bv[4];
#pragma unroll
        for (int mi = 0; mi < 4; ++mi) av[mi] = *(const f16x8*)(lds + bo + offA[mi]);
#pragma unroll
        for (int ni = 0; ni < 4; ++ni) bv[ni] = *(const f16x8*)(lds + bo + offB[ni]);
        __builtin_amdgcn_s_setprio(1);
#pragma unroll
        for (int mi = 0; mi < 4; ++mi)
#pragma unroll
            for (int ni = 0; ni < 4; ++ni)
                acc[mi][ni] = __builtin_amdgcn_mfma_f32_16x16x32_f16(av[mi], bv[ni], acc[mi][ni], 0, 0, 0);
        __builtin_amdgcn_s_setprio(0);
    }
#undef STAGE

    __syncthreads();   // full drain before LDS reuse as epilogue scratch

    float swv[8];
#pragma unroll
    for (int m = 0; m < 8; ++m) swv[m] = wsf[m];

    // epilogue: transpose each 16x16 fragment via per-wave LDS scratch
    float* sc = (float*)lds + wid * 1296;   // 8 regions of 4x324 floats (16 rows * 20 + pad)
    int bl = lane & 15, oi = lane >> 4;
    int o = nx * 8 + wc * 4 + oi;
    float biasv = bias[o];

#pragma unroll
    for (int mi = 0; mi < 4; ++mi) {
#pragma unroll
        for (int ni = 0; ni < 4; ++ni)
#pragma unroll
            for (int r = 0; r < 4; ++r)
                sc[ni * 324 + (oi * 4 + r) * 20 + bl] = acc[mi][ni][r];
        __asm__ volatile("s_waitcnt lgkmcnt(0)" ::: "memory");

        float4 cnA = *(const float4*)(sc + oi * 324 + bl * 20 + 0);
        float4 cnB = *(const float4*)(sc + oi * 324 + bl * 20 + 4);
        float4 cdA = *(const float4*)(sc + oi * 324 + bl * 20 + 8);
        float4 cdB = *(const float4*)(sc + oi * 324 + bl * 20 + 12);
        float cn[8] = {cnA.x, cnA.y, cnA.z, cnA.w, cnB.x, cnB.y, cnB.z, cnB.w};
        float cd[8] = {cdA.x, cdA.y, cdA.z, cdA.w, cdB.x, cdB.y, cdB.z, cdB.w};

        int b = b0 + wr * 64 + mi * 16 + bl;
        float basev = (float)baseh[(size_t)b * FOUT + o];
        float K0 = basev + biasv;
        bool empty = cnts[b] > 0;

        float mix = 0.f, num0 = 0.f;
#pragma unroll
        for (int m = 0; m < 8; ++m) {
            float num = K0 + cn[m];
            if (m == 0) num0 = num;
            float rs  = frsq(fmaxf(cd[m], 1e-20f));   // 1/den  (den = sqrt(cd), cd >= ~1e-4 on real data)
            float den = cd[m] * rs;                   // sqrt(cd)
            float z   = num * rs;
            float az  = fabsf(z);
            float E   = fexp2((z * z) * -0.72134752044448170f);   // exp(-z^2/2)
            // Q(az)/E via A&S 26.2.17 (x0.5 folded into coeffs): u = Q/E
            float t1  = frcp(fmaf(0.2316419f, az, 1.0f));
            float h   = fmaf(t1, 0.5307027145f, -0.7265760135f);
            h = fmaf(t1, h, 0.7107068705f);
            h = fmaf(t1, h, -0.142248368f);
            h = fmaf(t1, h, 0.127414796f);
            float u   = t1 * h;
            float v   = fmaf(-az, u, 0.3989422804014327f);  // (pdf - az*Q)/E
            float g   = fmaf(E, v, fmaxf(z, 0.f));          // pdf + z*cdf
            mix = fmaf(swv[m], den * g, mix);
        }
        out[(size_t)b * FOUT + o] = empty ? mix : fmaxf(num0, 0.f);
    }
}

extern "C" void kernel_launch(void* const* d_in, const int* in_sizes, int n_in,
                              void* d_out, int out_size, void* d_ws, size_t ws_size,
                              hipStream_t stream) {
    const float* x        = (const float*)d_in[0];
    const float* W        = (const float*)d_in[1];
    const float* bvec     = (const float*)d_in[2];
    const float* mean_p   = (const float*)d_in[3];
    const float* log_std2 = (const float*)d_in[4];
    const float* lw       = (const float*)d_in[5];
    float* out = (float*)d_out;

    char* wsb = (char*)d_ws;
    float*     wsf  = (float*)wsb;
    int*       cnts = (int*)(wsb + WSB_CNT);
    _Float16*  base = (_Float16*)(wsb + WSB_BASE);
    _Float16*  xch  = (_Float16*)(wsb + WSB_XCH);
    _Float16*  msk  = (_Float16*)(wsb + WSB_MSK);
    _Float16*  Wh   = (_Float16*)(wsb + WSB_WH);
    _Float16*  bct  = (_Float16*)(wsb + WSB_BCT);

    prep_bct <<<B_ROWS / 4, 256, 0, stream>>>(W, mean_p, log_std2, bct, Wh);
    prep_rows<<<B_ROWS / 4, 256, 0, stream>>>(x, xch, msk, cnts, lw, wsf);
    gemm_base<<<dim3(FOUT / 64, B_ROWS / 128), 256, 0, stream>>>(xch, Wh, base);
    gmm_fused<<<(B_ROWS / 256) * (8192 / 128), 512, 0, stream>>>(msk, bct, wsf, cnts, base, bvec, out);
}